// Round 4
// baseline (967.422 us; speedup 1.0000x reference)
//
#include <hip/hip_runtime.h>
#include <stdint.h>

#define NN 100000
#define NE 1600000
#define NG 64
#define DIN 128
#define HID 256
#define NATTR 8

typedef unsigned short u16;
typedef __attribute__((ext_vector_type(8))) short s16x8;
typedef __attribute__((ext_vector_type(4))) float f32x4;

__device__ __forceinline__ int imaxi(int a, int b) { return a > b ? a : b; }
__device__ __forceinline__ u16 f2bf(float f) {
    unsigned u = __float_as_uint(f);
    unsigned r = (u + 0x7fffu + ((u >> 16) & 1u)) >> 16;  // RNE
    return (u16)r;
}

// ---------------- init: zero deg_in, deg_out, P, gcnt ----------------

__global__ void k_init(int* __restrict__ deg_in, int* __restrict__ deg_out,
                       float* __restrict__ P, int* __restrict__ gcnt) {
    int i = blockIdx.x * 256 + threadIdx.x;
    if (i < NN) { deg_in[i] = 0; deg_out[i] = 0; }
    if (i < 128 * HID) P[i] = 0.f;
    if (i < NG) gcnt[i] = 0;
}

// ---------------- cast x -> bf16 + transpose W1l/W1r -> bf16 [n][k] ----------------

__global__ void k_cast_tw(const float4* __restrict__ x4, ushort4* __restrict__ xb4,
                          const float* __restrict__ W1l, const float* __restrict__ W1r,
                          u16* __restrict__ W1lt, u16* __restrict__ W1rt) {
    int i = blockIdx.x * 256 + threadIdx.x;
    const int NX4 = NN * DIN / 4;  // 3,200,000
    if (i < NX4) {
        float4 v = x4[i];
        ushort4 o;
        o.x = f2bf(v.x); o.y = f2bf(v.y); o.z = f2bf(v.z); o.w = f2bf(v.w);
        xb4[i] = o;
    } else {
        int j = i - NX4;
        if (j < 32768) {
            int n = j >> 7, k = j & 127;
            W1lt[j] = f2bf(W1l[k * HID + n]);
        } else if (j < 65536) {
            int jj = j - 32768;
            int n = jj >> 7, k = jj & 127;
            W1rt[jj] = f2bf(W1r[k * HID + n]);
        }
    }
}

// ---------------- CSR build (both directions) ----------------

__global__ void k_count2(const int* __restrict__ ei, int* __restrict__ deg_in,
                         int* __restrict__ deg_out) {
    int e = blockIdx.x * 256 + threadIdx.x;
    if (e < NE) {
        atomicAdd(&deg_in[ei[NE + e]], 1);
        atomicAdd(&deg_out[ei[e]], 1);
    }
}

__global__ void k_scan_part2(const int* __restrict__ deg_in, const int* __restrict__ deg_out,
                             int* __restrict__ part_in, int* __restrict__ part_out) {
    __shared__ int r1[256], r2[256];
    int t = threadIdx.x;
    int base = blockIdx.x * 1024 + t * 4;
    int a = 0, b = 0;
#pragma unroll
    for (int j = 0; j < 4; j++) {
        int i = base + j;
        if (i < NN) { a += deg_in[i]; b += deg_out[i]; }
    }
    r1[t] = a; r2[t] = b; __syncthreads();
    for (int off = 128; off > 0; off >>= 1) {
        if (t < off) { r1[t] += r1[t + off]; r2[t] += r2[t + off]; }
        __syncthreads();
    }
    if (t == 0) { part_in[blockIdx.x] = r1[0]; part_out[blockIdx.x] = r2[0]; }
}

__global__ void k_scan_top2(const int* __restrict__ part_in, const int* __restrict__ part_out,
                            int* __restrict__ poff_in, int* __restrict__ poff_out, int nchunks) {
    if (threadIdx.x == 0) {
        int a = 0, b = 0;
        for (int i = 0; i < nchunks; i++) {
            poff_in[i] = a; a += part_in[i];
            poff_out[i] = b; b += part_out[i];
        }
    }
}

__global__ void k_scan_final2(const int* __restrict__ deg_in, const int* __restrict__ deg_out,
                              const int* __restrict__ poff_in, const int* __restrict__ poff_out,
                              int* __restrict__ rowptr_in, int* __restrict__ cursor_in,
                              float* __restrict__ invdeg,
                              int* __restrict__ rowptr_out, int* __restrict__ cursor_out,
                              const int* __restrict__ batch, int* __restrict__ gcnt) {
    __shared__ int arr[256];
    __shared__ int lc[NG];
    int t = threadIdx.x;
    int base = blockIdx.x * 1024 + t * 4;
    if (t < NG) lc[t] = 0;

    // ---- pass A: in-degree ----
    int v[4];
#pragma unroll
    for (int j = 0; j < 4; j++) { int i = base + j; v[j] = (i < NN) ? deg_in[i] : 0; }
    int T = v[0] + v[1] + v[2] + v[3];
    arr[t] = T; __syncthreads();
    for (int off = 1; off < 256; off <<= 1) {
        int add = (t >= off) ? arr[t - off] : 0;
        __syncthreads();
        arr[t] += add;
        __syncthreads();
    }
    int ex = poff_in[blockIdx.x] + arr[t] - T;
    int pre = 0;
#pragma unroll
    for (int j = 0; j < 4; j++) {
        int i = base + j;
        int val = ex + pre;
        if (i <= NN) rowptr_in[i] = val;
        if (i < NN) {
            cursor_in[i] = val;
            invdeg[i] = 1.0f / (float)imaxi(v[j], 1);
            atomicAdd(&lc[batch[i]], 1);
        }
        pre += v[j];
    }
    __syncthreads();

    // ---- pass B: out-degree ----
#pragma unroll
    for (int j = 0; j < 4; j++) { int i = base + j; v[j] = (i < NN) ? deg_out[i] : 0; }
    T = v[0] + v[1] + v[2] + v[3];
    arr[t] = T; __syncthreads();
    for (int off = 1; off < 256; off <<= 1) {
        int add = (t >= off) ? arr[t - off] : 0;
        __syncthreads();
        arr[t] += add;
        __syncthreads();
    }
    ex = poff_out[blockIdx.x] + arr[t] - T;
    pre = 0;
#pragma unroll
    for (int j = 0; j < 4; j++) {
        int i = base + j;
        int val = ex + pre;
        if (i <= NN) rowptr_out[i] = val;
        if (i < NN) cursor_out[i] = val;
        pre += v[j];
    }
    __syncthreads();
    if (t < NG && lc[t] > 0) atomicAdd(&gcnt[t], lc[t]);
}

__global__ void k_fill2(const int* __restrict__ ei, int* __restrict__ cursor_in,
                        int* __restrict__ cursor_out, int* __restrict__ col_in,
                        int* __restrict__ col_out) {
    int e = blockIdx.x * 256 + threadIdx.x;
    if (e < NE) {
        int s = ei[e], d = ei[NE + e];
        col_in[atomicAdd(&cursor_in[d], 1)] = s;
        col_out[atomicAdd(&cursor_out[s], 1)] = d;
    }
}

// ---------------- layer-1 mean aggregation, XCD-pinned feature chunks ----------------
// chunk = blockIdx.x & 7 -> round-robin XCD; each chunk's xb slice = 3.2 MB (fits 4 MB L2).
// Wave: 8 neighbor slots x 8 feat-dwords; shuffle-reduce over slots.

__global__ void k_agg(const unsigned* __restrict__ xb, unsigned* __restrict__ agg1,
                      const int* __restrict__ rowptr, const int* __restrict__ col) {
    int chunk = blockIdx.x & 7;
    int grp   = blockIdx.x >> 3;
    int node  = grp * 4 + (threadIdx.x >> 6);
    if (node >= NN) return;
    int lane = threadIdx.x & 63;
    int n8 = lane >> 3, fl = lane & 7;
    int s = rowptr[node], e = rowptr[node + 1];
    float ax = 0.f, ay = 0.f;
    for (int i = s + n8; i < e; i += 8) {
        int u = col[i];
        unsigned w = xb[(size_t)u * 64 + chunk * 8 + fl];
        ax += __uint_as_float(w << 16);
        ay += __uint_as_float(w & 0xffff0000u);
    }
    ax += __shfl_xor(ax, 8);  ay += __shfl_xor(ay, 8);
    ax += __shfl_xor(ax, 16); ay += __shfl_xor(ay, 16);
    ax += __shfl_xor(ax, 32); ay += __shfl_xor(ay, 32);
    if (n8 == 0) {
        float inv = 1.f / (float)imaxi(e - s, 1);
        unsigned o = (((unsigned)f2bf(ay * inv)) << 16) | (unsigned)f2bf(ax * inv);
        agg1[(size_t)node * 64 + chunk * 8 + fl] = o;
    }
}

// ---------------- MFMA GEMM1: h1t = relu(agg1@W1l + x@W1r + b1)^T ----------------

__global__ __launch_bounds__(256) void k_gemm1(
    const u16* __restrict__ agg1, const u16* __restrict__ xb,
    const u16* __restrict__ W1lt, const u16* __restrict__ W1rt,
    const float* __restrict__ b1, u16* __restrict__ h1t) {
    __shared__ u16 As[128][40];
    __shared__ u16 Bs[128][40];
    int t = threadIdx.x;
    int m0 = blockIdx.x * 128;
    int n0 = blockIdx.y * 128;
    int wave = t >> 6, lane = t & 63;
    int wm = wave & 1, wn = wave >> 1;
    int lm = lane & 15, quad = lane >> 4;
    f32x4 acc[4][4] = {};
    const u16* Ap = agg1;
    const u16* Bp = W1lt;
#pragma unroll
    for (int ph = 0; ph < 2; ph++) {
        for (int k0 = 0; k0 < DIN; k0 += 32) {
#pragma unroll
            for (int i = 0; i < 2; i++) {
                int flat = t + i * 256;
                int r = flat >> 2, q = flat & 3;
                int m = m0 + r;
                uint4 v = {0u, 0u, 0u, 0u};
                if (m < NN) v = *(const uint4*)(Ap + (size_t)m * DIN + k0 + q * 8);
                *(uint4*)&As[r][q * 8] = v;
                uint4 w = *(const uint4*)(Bp + (size_t)(n0 + r) * DIN + k0 + q * 8);
                *(uint4*)&Bs[r][q * 8] = w;
            }
            __syncthreads();
            s16x8 af[4], bfr[4];
#pragma unroll
            for (int i = 0; i < 4; i++) {
                af[i]  = *(const s16x8*)&As[wm * 64 + i * 16 + lm][quad * 8];
                bfr[i] = *(const s16x8*)&Bs[wn * 64 + i * 16 + lm][quad * 8];
            }
#pragma unroll
            for (int mi = 0; mi < 4; mi++)
#pragma unroll
                for (int ni = 0; ni < 4; ni++)
                    acc[mi][ni] = __builtin_amdgcn_mfma_f32_16x16x32_bf16(
                        af[mi], bfr[ni], acc[mi][ni], 0, 0, 0);
            __syncthreads();
        }
        Ap = xb; Bp = W1rt;
    }
#pragma unroll
    for (int ni = 0; ni < 4; ni++) {
        int colf = n0 + wn * 64 + ni * 16 + lm;  // feature
        float bias = b1[colf];
#pragma unroll
        for (int mi = 0; mi < 4; mi++) {
            int row = m0 + wm * 64 + mi * 16 + quad * 4;  // node
            if (row < NN) {
                ushort4 o;
                o.x = f2bf(fmaxf(acc[mi][ni][0] + bias, 0.f));
                o.y = f2bf(fmaxf(acc[mi][ni][1] + bias, 0.f));
                o.z = f2bf(fmaxf(acc[mi][ni][2] + bias, 0.f));
                o.w = f2bf(fmaxf(acc[mi][ni][3] + bias, 0.f));
                *(ushort4*)(h1t + (size_t)colf * NN + row) = o;
            }
        }
    }
}

// ---------------- atomic-free Wbt build (bf16, row-major [g][u]) ----------------
// Per 64-node tile: LDS bins[u_local][128]; out-edges accumulate invdeg[dst] into
// bin batch[dst]; indicator at 64+batch[u]; coalesced bf16 tile write.

__global__ __launch_bounds__(256) void k_buildw(
    const int* __restrict__ rowptr_out, const int* __restrict__ col_out,
    const int* __restrict__ batch, const float* __restrict__ invdeg,
    u16* __restrict__ Wbt) {
    __shared__ float tile[64][129];
    int t = threadIdx.x;
    int u0 = blockIdx.x * 64;
    for (int i = t; i < 64 * 129; i += 256) ((float*)tile)[i] = 0.f;
    __syncthreads();
    int ul = t >> 2, qtr = t & 3;
    int u = u0 + ul;
    if (u < NN) {
        if (qtr == 0) tile[ul][64 + batch[u]] = 1.0f;
        int s = rowptr_out[u], e = rowptr_out[u + 1];
        for (int i = s + qtr; i < e; i += 4) {
            int d = col_out[i];
            atomicAdd(&tile[ul][batch[d]], invdeg[d]);
        }
    }
    __syncthreads();
    // write 128 g-rows x 64 u-cols; thread: g = t & 127, u-half = (t>>7)*32
    int g = t & 127;
    int ub = (t >> 7) * 32;
    for (int c = 0; c < 32; c += 4) {
        int uu = u0 + ub + c;
        if (uu < NN) {  // NN % 4 == 0
            ushort4 o;
            o.x = f2bf(tile[ub + c + 0][g]);
            o.y = f2bf(tile[ub + c + 1][g]);
            o.z = f2bf(tile[ub + c + 2][g]);
            o.w = f2bf(tile[ub + c + 3][g]);
            *(ushort4*)(Wbt + (size_t)g * NN + uu) = o;
        }
    }
}

// ---------------- pool GEMM (split-K MFMA): P[128][256] = Wbt @ h1t^T ----------------

#define KCHUNK 512

__global__ __launch_bounds__(256) void k_poolg(
    const u16* __restrict__ Wbt, const u16* __restrict__ h1t, float* __restrict__ P) {
    __shared__ u16 As[128][40];
    __shared__ u16 Bs[128][40];
    int t = threadIdx.x;
    int kbase = blockIdx.x * KCHUNK;
    int n0 = blockIdx.y * 128;
    int krem = NN - kbase;
    int ksteps = (krem < KCHUNK ? krem : KCHUNK) >> 5;
    int wave = t >> 6, lane = t & 63;
    int wm = wave & 1, wn = wave >> 1;
    int lm = lane & 15, quad = lane >> 4;
    f32x4 acc[4][4] = {};
    for (int ks = 0; ks < ksteps; ks++) {
        int k0 = kbase + ks * 32;
#pragma unroll
        for (int i = 0; i < 2; i++) {
            int flat = t + i * 256;
            int r = flat >> 2, q = flat & 3;
            uint4 v = *(const uint4*)(Wbt + (size_t)r * NN + k0 + q * 8);
            *(uint4*)&As[r][q * 8] = v;
            uint4 w = *(const uint4*)(h1t + (size_t)(n0 + r) * NN + k0 + q * 8);
            *(uint4*)&Bs[r][q * 8] = w;
        }
        __syncthreads();
        s16x8 af[4], bfr[4];
#pragma unroll
        for (int i = 0; i < 4; i++) {
            af[i]  = *(const s16x8*)&As[wm * 64 + i * 16 + lm][quad * 8];
            bfr[i] = *(const s16x8*)&Bs[wn * 64 + i * 16 + lm][quad * 8];
        }
#pragma unroll
        for (int mi = 0; mi < 4; mi++)
#pragma unroll
            for (int ni = 0; ni < 4; ni++)
                acc[mi][ni] = __builtin_amdgcn_mfma_f32_16x16x32_bf16(
                    af[mi], bfr[ni], acc[mi][ni], 0, 0, 0);
        __syncthreads();
    }
#pragma unroll
    for (int mi = 0; mi < 4; mi++)
#pragma unroll
        for (int ni = 0; ni < 4; ni++) {
            int gcol = wm * 64 + mi * 16 + quad * 4;
            int feat = n0 + wn * 64 + ni * 16 + lm;
#pragma unroll
            for (int r = 0; r < 4; r++)
                atomicAdd(&P[(gcol + r) * HID + feat], acc[mi][ni][r]);
        }
}

// ---------------- head ----------------

__global__ void k_head(const float* __restrict__ P, const int* __restrict__ gcnt,
                       const float* __restrict__ gattr,
                       const float* __restrict__ W2l, const float* __restrict__ b2,
                       const float* __restrict__ W2r,
                       const float* __restrict__ Wf1, const float* __restrict__ bf1,
                       const float* __restrict__ Wf2, const float* __restrict__ bf2v,
                       float* __restrict__ out) {
    __shared__ float pa[HID], ph[HID], gv[HID + NATTR];
    __shared__ float red[256];
    int g = blockIdx.x, t = threadIdx.x;
    pa[t] = P[g * HID + t];
    ph[t] = P[(NG + g) * HID + t];
    __syncthreads();
    float s = 0.f;
    for (int k = 0; k < HID; k++)
        s += pa[k] * W2l[k * HID + t] + ph[k] * W2r[k * HID + t];
    float invc = 1.f / (float)imaxi(gcnt[g], 1);
    gv[t] = s * invc + b2[t];
    if (t < NATTR) gv[HID + t] = gattr[g * NATTR + t];
    __syncthreads();
    float h = bf1[t];
    for (int k = 0; k < HID + NATTR; k++) h += gv[k] * Wf1[k * HID + t];
    h = fmaxf(h, 0.f);
    red[t] = h * Wf2[t];
    __syncthreads();
    for (int off = 128; off > 0; off >>= 1) {
        if (t < off) red[t] += red[t + off];
        __syncthreads();
    }
    if (t == 0) out[g] = red[0] + bf2v[0];
}

// ---------------- launch ----------------

extern "C" void kernel_launch(void* const* d_in, const int* in_sizes, int n_in,
                              void* d_out, int out_size, void* d_ws, size_t ws_size,
                              hipStream_t stream) {
    (void)in_sizes; (void)n_in; (void)out_size; (void)ws_size;
    const float* x     = (const float*)d_in[0];
    const int*   ei    = (const int*)d_in[1];
    const int*   batch = (const int*)d_in[2];
    const float* gattr = (const float*)d_in[3];
    const float* W1l   = (const float*)d_in[4];
    const float* b1    = (const float*)d_in[5];
    const float* W1r   = (const float*)d_in[6];
    const float* W2l   = (const float*)d_in[7];
    const float* b2    = (const float*)d_in[8];
    const float* W2r   = (const float*)d_in[9];
    const float* Wf1   = (const float*)d_in[10];
    const float* bf1   = (const float*)d_in[11];
    const float* Wf2   = (const float*)d_in[12];
    const float* bf2v  = (const float*)d_in[13];
    float* out = (float*)d_out;

    uint8_t* w = (uint8_t*)d_ws;
    size_t off = 0;
    auto alloc = [&](size_t bytes) -> void* {
        void* p = w + off;
        off += (bytes + 255) & ~(size_t)255;
        return p;
    };
    u16*   xb      = (u16*)alloc((size_t)NN * DIN * 2);     // 25.6 MB
    u16*   agg1    = (u16*)alloc((size_t)NN * DIN * 2);     // 25.6 MB
    u16*   h1t     = (u16*)alloc((size_t)NN * HID * 2);     // 51.2 MB
    u16*   Wbt     = (u16*)alloc((size_t)128 * NN * 2);     // 25.6 MB
    u16*   W1lt    = (u16*)alloc((size_t)HID * DIN * 2);
    u16*   W1rt    = (u16*)alloc((size_t)HID * DIN * 2);
    int*   deg_in  = (int*)alloc((size_t)NN * 4);
    int*   deg_out = (int*)alloc((size_t)NN * 4);
    float* invdeg  = (float*)alloc((size_t)NN * 4);
    int*   rp_in   = (int*)alloc((size_t)(NN + 1) * 4);
    int*   cu_in   = (int*)alloc((size_t)NN * 4);
    int*   rp_out  = (int*)alloc((size_t)(NN + 1) * 4);
    int*   cu_out  = (int*)alloc((size_t)NN * 4);
    int*   col_in  = (int*)alloc((size_t)NE * 4);           // 6.4 MB
    int*   col_out = (int*)alloc((size_t)NE * 4);           // 6.4 MB
    int*   part_in = (int*)alloc(128 * 4);
    int*   part_out= (int*)alloc(128 * 4);
    int*   poff_in = (int*)alloc(128 * 4);
    int*   poff_out= (int*)alloc(128 * 4);
    float* P       = (float*)alloc((size_t)128 * HID * 4);
    int*   gcnt    = (int*)alloc(NG * 4);

    const int nchunks = (NN + 1023) / 1024;  // 98

    k_init<<<(NN + 255) / 256, 256, 0, stream>>>(deg_in, deg_out, P, gcnt);
    k_cast_tw<<<(NN * DIN / 4 + 65536 + 255) / 256, 256, 0, stream>>>(
        (const float4*)x, (ushort4*)xb, W1l, W1r, W1lt, W1rt);

    k_count2<<<(NE + 255) / 256, 256, 0, stream>>>(ei, deg_in, deg_out);
    k_scan_part2<<<nchunks, 256, 0, stream>>>(deg_in, deg_out, part_in, part_out);
    k_scan_top2<<<1, 64, 0, stream>>>(part_in, part_out, poff_in, poff_out, nchunks);
    k_scan_final2<<<nchunks, 256, 0, stream>>>(deg_in, deg_out, poff_in, poff_out,
                                               rp_in, cu_in, invdeg, rp_out, cu_out,
                                               batch, gcnt);
    k_fill2<<<(NE + 255) / 256, 256, 0, stream>>>(ei, cu_in, cu_out, col_in, col_out);

    // layer 1: XCD-chunked gather + MFMA GEMM
    k_agg<<<((NN + 3) / 4) * 8, 256, 0, stream>>>((const unsigned*)xb, (unsigned*)agg1,
                                                  rp_in, col_in);
    dim3 g1((NN + 127) / 128, HID / 128);
    k_gemm1<<<g1, 256, 0, stream>>>(agg1, xb, W1lt, W1rt, b1, h1t);

    // pooled layer-2 coefficient matrix (atomic-free, bf16 direct)
    k_buildw<<<(NN + 63) / 64, 256, 0, stream>>>(rp_out, col_out, batch, invdeg, Wbt);

    dim3 g2((NN + KCHUNK - 1) / KCHUNK, HID / 128);
    k_poolg<<<g2, 256, 0, stream>>>(Wbt, h1t, P);

    k_head<<<NG, 256, 0, stream>>>(P, gcnt, gattr, W2l, b2, W2r, Wf1, bf1, Wf2, bf2v, out);
}

// Round 5
// 789.216 us; speedup vs baseline: 1.2258x; 1.2258x over previous
//
#include <hip/hip_runtime.h>
#include <stdint.h>

#define NN 100000
#define NE 1600000
#define NG 64
#define DIN 128
#define HID 256
#define NATTR 8
#define SL_NODES 12500  // NN / 8 slices (XCD-pinned scatter)

typedef unsigned short u16;
typedef __attribute__((ext_vector_type(8))) short s16x8;
typedef __attribute__((ext_vector_type(4))) float f32x4;

__device__ __forceinline__ int imaxi(int a, int b) { return a > b ? a : b; }
__device__ __forceinline__ u16 f2bf(float f) {
    unsigned u = __float_as_uint(f);
    unsigned r = (u + 0x7fffu + ((u >> 16) & 1u)) >> 16;  // RNE
    return (u16)r;
}

// ---------------- init: zero Wbt_f (51.2 MB), deg, P, gcnt ----------------

__global__ void k_init(int* __restrict__ deg, float4* __restrict__ Wbt4,
                       float* __restrict__ P, int* __restrict__ gcnt) {
    int i = blockIdx.x * 256 + threadIdx.x;
    if (i < 128 * NN / 4) Wbt4[i] = make_float4(0.f, 0.f, 0.f, 0.f);
    if (i < NN) deg[i] = 0;
    if (i < 128 * HID) P[i] = 0.f;
    if (i < NG) gcnt[i] = 0;
}

// ---------------- cast x -> bf16 + transpose W1l/W1r -> bf16 [n][k] ----------------

__global__ void k_cast_tw(const float4* __restrict__ x4, ushort4* __restrict__ xb4,
                          const float* __restrict__ W1l, const float* __restrict__ W1r,
                          u16* __restrict__ W1lt, u16* __restrict__ W1rt) {
    int i = blockIdx.x * 256 + threadIdx.x;
    const int NX4 = NN * DIN / 4;  // 3,200,000
    if (i < NX4) {
        float4 v = x4[i];
        ushort4 o;
        o.x = f2bf(v.x); o.y = f2bf(v.y); o.z = f2bf(v.z); o.w = f2bf(v.w);
        xb4[i] = o;
    } else {
        int j = i - NX4;
        if (j < 32768) {
            int n = j >> 7, k = j & 127;
            W1lt[j] = f2bf(W1l[k * HID + n]);
        } else if (j < 65536) {
            int jj = j - 32768;
            int n = jj >> 7, k = jj & 127;
            W1rt[jj] = f2bf(W1r[k * HID + n]);
        }
    }
}

// ---------------- CSR build (in-edges only) ----------------

__global__ void k_count(const int* __restrict__ ei, int* __restrict__ deg) {
    int e = blockIdx.x * 256 + threadIdx.x;
    if (e < NE) {
        int d = __builtin_nontemporal_load(&ei[NE + e]);
        atomicAdd(&deg[d], 1);
    }
}

__global__ void k_scan_part(const int* __restrict__ deg, int* __restrict__ part) {
    __shared__ int red[256];
    int t = threadIdx.x;
    int base = blockIdx.x * 1024 + t * 4;
    int s = 0;
#pragma unroll
    for (int j = 0; j < 4; j++) { int i = base + j; s += (i < NN) ? deg[i] : 0; }
    red[t] = s; __syncthreads();
    for (int off = 128; off > 0; off >>= 1) {
        if (t < off) red[t] += red[t + off];
        __syncthreads();
    }
    if (t == 0) part[blockIdx.x] = red[0];
}

__global__ void k_scan_top(const int* __restrict__ part, int* __restrict__ poff, int nchunks) {
    if (threadIdx.x == 0) {
        int run = 0;
        for (int i = 0; i < nchunks; i++) { poff[i] = run; run += part[i]; }
    }
}

// also: invdeg, gcnt, and the PH indicator rows of Wbt_f (rows 64..127)
__global__ void k_scan_final(const int* __restrict__ deg, const int* __restrict__ poff,
                             int* __restrict__ rowptr, int* __restrict__ cursor,
                             float* __restrict__ invdeg, const int* __restrict__ batch,
                             int* __restrict__ gcnt, float* __restrict__ Wbt_f) {
    __shared__ int arr[256];
    __shared__ int lc[NG];
    int t = threadIdx.x;
    int base = blockIdx.x * 1024 + t * 4;
    if (t < NG) lc[t] = 0;
    int v[4];
#pragma unroll
    for (int j = 0; j < 4; j++) { int i = base + j; v[j] = (i < NN) ? deg[i] : 0; }
    int T = v[0] + v[1] + v[2] + v[3];
    arr[t] = T; __syncthreads();
    for (int off = 1; off < 256; off <<= 1) {
        int add = (t >= off) ? arr[t - off] : 0;
        __syncthreads();
        arr[t] += add;
        __syncthreads();
    }
    int ex = poff[blockIdx.x] + arr[t] - T;
    int pre = 0;
#pragma unroll
    for (int j = 0; j < 4; j++) {
        int i = base + j;
        int val = ex + pre;
        if (i <= NN) rowptr[i] = val;
        if (i < NN) {
            cursor[i] = val;
            invdeg[i] = 1.0f / (float)imaxi(v[j], 1);
            int g = batch[i];
            atomicAdd(&lc[g], 1);
            Wbt_f[(size_t)(NG + g) * NN + i] = 1.0f;  // indicator (PH) row
        }
        pre += v[j];
    }
    __syncthreads();
    if (t < NG && lc[t] > 0) atomicAdd(&gcnt[t], lc[t]);
}

// ---------------- XCD-sliced CSR fill ----------------
// slice = blockIdx.x & 7 -> one XCD; only edges with dst in slice are scattered,
// so col writes are confined to ~800 KB (L2-resident; no write amplification).

__global__ void k_fill_s(const int* __restrict__ ei, int* __restrict__ cursor,
                         int* __restrict__ col) {
    int slice = blockIdx.x & 7;
    int blk = blockIdx.x >> 3;
    int nthr = (gridDim.x >> 3) * 256;
    int lo = slice * SL_NODES, hi = lo + SL_NODES;
    for (int e = blk * 256 + threadIdx.x; e < NE; e += nthr) {
        int d = __builtin_nontemporal_load(&ei[NE + e]);
        if (d >= lo && d < hi) {
            int s = __builtin_nontemporal_load(&ei[e]);
            col[atomicAdd(&cursor[d], 1)] = s;
        }
    }
}

// ---------------- XCD-sliced Wbt build (f32 atomics, rows 0..63) ----------------
// slice by src: atomics confined to a 64 x 12500 f32 = 3.2 MB slice (fits 4 MB L2).

__global__ void k_buildw_s(const int* __restrict__ ei, const int* __restrict__ batch,
                           const float* __restrict__ invdeg, float* __restrict__ Wbt_f) {
    int slice = blockIdx.x & 7;
    int blk = blockIdx.x >> 3;
    int nthr = (gridDim.x >> 3) * 256;
    int lo = slice * SL_NODES, hi = lo + SL_NODES;
    for (int e = blk * 256 + threadIdx.x; e < NE; e += nthr) {
        int s = __builtin_nontemporal_load(&ei[e]);
        if (s >= lo && s < hi) {
            int d = __builtin_nontemporal_load(&ei[NE + e]);
            atomicAdd(&Wbt_f[(size_t)batch[d] * NN + s], invdeg[d]);
        }
    }
}

// ---------------- Wbt f32 -> bf16 ----------------

__global__ void k_castw(const float4* __restrict__ src, ushort4* __restrict__ dst) {
    int i = blockIdx.x * 256 + threadIdx.x;
    if (i < 128 * NN / 4) {
        float4 v = src[i];
        ushort4 o;
        o.x = f2bf(v.x); o.y = f2bf(v.y); o.z = f2bf(v.z); o.w = f2bf(v.w);
        dst[i] = o;
    }
}

// ---------------- layer-1 mean aggregation, XCD-pinned feature chunks ----------------
// chunk = blockIdx.x & 7: each XCD re-reads only a 3.2 MB slice of xb (L2-resident).
// Wave: 8 neighbor slots x 8 feat-dwords; shuffle-reduce over slots.

__global__ void k_agg(const unsigned* __restrict__ xb, unsigned* __restrict__ agg1,
                      const int* __restrict__ rowptr, const int* __restrict__ col) {
    int chunk = blockIdx.x & 7;
    int grp   = blockIdx.x >> 3;
    int node  = grp * 4 + (threadIdx.x >> 6);
    if (node >= NN) return;
    int lane = threadIdx.x & 63;
    int n8 = lane >> 3, fl = lane & 7;
    int s = rowptr[node], e = rowptr[node + 1];
    float ax = 0.f, ay = 0.f;
    for (int i = s + n8; i < e; i += 8) {
        int u = col[i];
        unsigned w = xb[(size_t)u * 64 + chunk * 8 + fl];
        ax += __uint_as_float(w << 16);
        ay += __uint_as_float(w & 0xffff0000u);
    }
    ax += __shfl_xor(ax, 8);  ay += __shfl_xor(ay, 8);
    ax += __shfl_xor(ax, 16); ay += __shfl_xor(ay, 16);
    ax += __shfl_xor(ax, 32); ay += __shfl_xor(ay, 32);
    if (n8 == 0) {
        float inv = 1.f / (float)imaxi(e - s, 1);
        unsigned o = (((unsigned)f2bf(ay * inv)) << 16) | (unsigned)f2bf(ax * inv);
        agg1[(size_t)node * 64 + chunk * 8 + fl] = o;
    }
}

// ---------------- MFMA GEMM1: h1t = relu(agg1@W1l + x@W1r + b1)^T ----------------

__global__ __launch_bounds__(256) void k_gemm1(
    const u16* __restrict__ agg1, const u16* __restrict__ xb,
    const u16* __restrict__ W1lt, const u16* __restrict__ W1rt,
    const float* __restrict__ b1, u16* __restrict__ h1t) {
    __shared__ u16 As[128][40];
    __shared__ u16 Bs[128][40];
    int t = threadIdx.x;
    int m0 = blockIdx.x * 128;
    int n0 = blockIdx.y * 128;
    int wave = t >> 6, lane = t & 63;
    int wm = wave & 1, wn = wave >> 1;
    int lm = lane & 15, quad = lane >> 4;
    f32x4 acc[4][4] = {};
    const u16* Ap = agg1;
    const u16* Bp = W1lt;
#pragma unroll
    for (int ph = 0; ph < 2; ph++) {
        for (int k0 = 0; k0 < DIN; k0 += 32) {
#pragma unroll
            for (int i = 0; i < 2; i++) {
                int flat = t + i * 256;
                int r = flat >> 2, q = flat & 3;
                int m = m0 + r;
                uint4 v = {0u, 0u, 0u, 0u};
                if (m < NN) v = *(const uint4*)(Ap + (size_t)m * DIN + k0 + q * 8);
                *(uint4*)&As[r][q * 8] = v;
                uint4 w = *(const uint4*)(Bp + (size_t)(n0 + r) * DIN + k0 + q * 8);
                *(uint4*)&Bs[r][q * 8] = w;
            }
            __syncthreads();
            s16x8 af[4], bfr[4];
#pragma unroll
            for (int i = 0; i < 4; i++) {
                af[i]  = *(const s16x8*)&As[wm * 64 + i * 16 + lm][quad * 8];
                bfr[i] = *(const s16x8*)&Bs[wn * 64 + i * 16 + lm][quad * 8];
            }
#pragma unroll
            for (int mi = 0; mi < 4; mi++)
#pragma unroll
                for (int ni = 0; ni < 4; ni++)
                    acc[mi][ni] = __builtin_amdgcn_mfma_f32_16x16x32_bf16(
                        af[mi], bfr[ni], acc[mi][ni], 0, 0, 0);
            __syncthreads();
        }
        Ap = xb; Bp = W1rt;
    }
#pragma unroll
    for (int ni = 0; ni < 4; ni++) {
        int colf = n0 + wn * 64 + ni * 16 + lm;  // feature
        float bias = b1[colf];
#pragma unroll
        for (int mi = 0; mi < 4; mi++) {
            int row = m0 + wm * 64 + mi * 16 + quad * 4;  // node
            if (row < NN) {
                ushort4 o;
                o.x = f2bf(fmaxf(acc[mi][ni][0] + bias, 0.f));
                o.y = f2bf(fmaxf(acc[mi][ni][1] + bias, 0.f));
                o.z = f2bf(fmaxf(acc[mi][ni][2] + bias, 0.f));
                o.w = f2bf(fmaxf(acc[mi][ni][3] + bias, 0.f));
                *(ushort4*)(h1t + (size_t)colf * NN + row) = o;
            }
        }
    }
}

// ---------------- pool GEMM (split-K MFMA): P[128][256] = Wbt @ h1t^T ----------------

#define KCHUNK 1024

__global__ __launch_bounds__(256) void k_poolg(
    const u16* __restrict__ Wbt, const u16* __restrict__ h1t, float* __restrict__ P) {
    __shared__ u16 As[128][40];
    __shared__ u16 Bs[128][40];
    int t = threadIdx.x;
    int kbase = blockIdx.x * KCHUNK;
    int n0 = blockIdx.y * 128;
    int krem = NN - kbase;
    int ksteps = (krem < KCHUNK ? krem : KCHUNK) >> 5;
    int wave = t >> 6, lane = t & 63;
    int wm = wave & 1, wn = wave >> 1;
    int lm = lane & 15, quad = lane >> 4;
    f32x4 acc[4][4] = {};
    for (int ks = 0; ks < ksteps; ks++) {
        int k0 = kbase + ks * 32;
#pragma unroll
        for (int i = 0; i < 2; i++) {
            int flat = t + i * 256;
            int r = flat >> 2, q = flat & 3;
            uint4 v = *(const uint4*)(Wbt + (size_t)r * NN + k0 + q * 8);
            *(uint4*)&As[r][q * 8] = v;
            uint4 w = *(const uint4*)(h1t + (size_t)(n0 + r) * NN + k0 + q * 8);
            *(uint4*)&Bs[r][q * 8] = w;
        }
        __syncthreads();
        s16x8 af[4], bfr[4];
#pragma unroll
        for (int i = 0; i < 4; i++) {
            af[i]  = *(const s16x8*)&As[wm * 64 + i * 16 + lm][quad * 8];
            bfr[i] = *(const s16x8*)&Bs[wn * 64 + i * 16 + lm][quad * 8];
        }
#pragma unroll
        for (int mi = 0; mi < 4; mi++)
#pragma unroll
            for (int ni = 0; ni < 4; ni++)
                acc[mi][ni] = __builtin_amdgcn_mfma_f32_16x16x32_bf16(
                    af[mi], bfr[ni], acc[mi][ni], 0, 0, 0);
        __syncthreads();
    }
#pragma unroll
    for (int mi = 0; mi < 4; mi++)
#pragma unroll
        for (int ni = 0; ni < 4; ni++) {
            int gcol = wm * 64 + mi * 16 + quad * 4;
            int feat = n0 + wn * 64 + ni * 16 + lm;
#pragma unroll
            for (int r = 0; r < 4; r++)
                atomicAdd(&P[(gcol + r) * HID + feat], acc[mi][ni][r]);
        }
}

// ---------------- head ----------------

__global__ void k_head(const float* __restrict__ P, const int* __restrict__ gcnt,
                       const float* __restrict__ gattr,
                       const float* __restrict__ W2l, const float* __restrict__ b2,
                       const float* __restrict__ W2r,
                       const float* __restrict__ Wf1, const float* __restrict__ bf1,
                       const float* __restrict__ Wf2, const float* __restrict__ bf2v,
                       float* __restrict__ out) {
    __shared__ float pa[HID], ph[HID], gv[HID + NATTR];
    __shared__ float red[256];
    int g = blockIdx.x, t = threadIdx.x;
    pa[t] = P[g * HID + t];
    ph[t] = P[(NG + g) * HID + t];
    __syncthreads();
    float s = 0.f;
    for (int k = 0; k < HID; k++)
        s += pa[k] * W2l[k * HID + t] + ph[k] * W2r[k * HID + t];
    float invc = 1.f / (float)imaxi(gcnt[g], 1);
    gv[t] = s * invc + b2[t];
    if (t < NATTR) gv[HID + t] = gattr[g * NATTR + t];
    __syncthreads();
    float h = bf1[t];
    for (int k = 0; k < HID + NATTR; k++) h += gv[k] * Wf1[k * HID + t];
    h = fmaxf(h, 0.f);
    red[t] = h * Wf2[t];
    __syncthreads();
    for (int off = 128; off > 0; off >>= 1) {
        if (t < off) red[t] += red[t + off];
        __syncthreads();
    }
    if (t == 0) out[g] = red[0] + bf2v[0];
}

// ---------------- launch ----------------

extern "C" void kernel_launch(void* const* d_in, const int* in_sizes, int n_in,
                              void* d_out, int out_size, void* d_ws, size_t ws_size,
                              hipStream_t stream) {
    (void)in_sizes; (void)n_in; (void)out_size; (void)ws_size;
    const float* x     = (const float*)d_in[0];
    const int*   ei    = (const int*)d_in[1];
    const int*   batch = (const int*)d_in[2];
    const float* gattr = (const float*)d_in[3];
    const float* W1l   = (const float*)d_in[4];
    const float* b1    = (const float*)d_in[5];
    const float* W1r   = (const float*)d_in[6];
    const float* W2l   = (const float*)d_in[7];
    const float* b2    = (const float*)d_in[8];
    const float* W2r   = (const float*)d_in[9];
    const float* Wf1   = (const float*)d_in[10];
    const float* bf1   = (const float*)d_in[11];
    const float* Wf2   = (const float*)d_in[12];
    const float* bf2v  = (const float*)d_in[13];
    float* out = (float*)d_out;

    uint8_t* w = (uint8_t*)d_ws;
    size_t off = 0;
    auto alloc = [&](size_t bytes) -> void* {
        void* p = w + off;
        off += (bytes + 255) & ~(size_t)255;
        return p;
    };
    u16*   xb     = (u16*)alloc((size_t)NN * DIN * 2);     // 25.6 MB
    u16*   agg1   = (u16*)alloc((size_t)NN * DIN * 2);     // 25.6 MB
    u16*   h1t    = (u16*)alloc((size_t)NN * HID * 2);     // 51.2 MB
    float* Wbt_f  = (float*)alloc((size_t)128 * NN * 4);   // 51.2 MB
    u16*   Wbt    = (u16*)alloc((size_t)128 * NN * 2);     // 25.6 MB
    u16*   W1lt   = (u16*)alloc((size_t)HID * DIN * 2);
    u16*   W1rt   = (u16*)alloc((size_t)HID * DIN * 2);
    int*   deg    = (int*)alloc((size_t)NN * 4);
    float* invdeg = (float*)alloc((size_t)NN * 4);
    int*   rowptr = (int*)alloc((size_t)(NN + 1) * 4);
    int*   cursor = (int*)alloc((size_t)NN * 4);
    int*   col    = (int*)alloc((size_t)NE * 4);           // 6.4 MB
    int*   part   = (int*)alloc(128 * 4);
    int*   poff   = (int*)alloc(128 * 4);
    float* P      = (float*)alloc((size_t)128 * HID * 4);
    int*   gcnt   = (int*)alloc(NG * 4);

    const int nchunks = (NN + 1023) / 1024;  // 98

    k_init<<<(128 * NN / 4 + 255) / 256, 256, 0, stream>>>(deg, (float4*)Wbt_f, P, gcnt);
    k_cast_tw<<<(NN * DIN / 4 + 65536 + 255) / 256, 256, 0, stream>>>(
        (const float4*)x, (ushort4*)xb, W1l, W1r, W1lt, W1rt);

    k_count<<<(NE + 255) / 256, 256, 0, stream>>>(ei, deg);
    k_scan_part<<<nchunks, 256, 0, stream>>>(deg, part);
    k_scan_top<<<1, 64, 0, stream>>>(part, poff, nchunks);
    k_scan_final<<<nchunks, 256, 0, stream>>>(deg, poff, rowptr, cursor, invdeg,
                                              batch, gcnt, Wbt_f);
    k_fill_s<<<1024, 256, 0, stream>>>(ei, cursor, col);

    // layer 1
    k_agg<<<(NN / 4) * 8, 256, 0, stream>>>((const unsigned*)xb, (unsigned*)agg1,
                                            rowptr, col);
    dim3 g1((NN + 127) / 128, HID / 128);
    k_gemm1<<<g1, 256, 0, stream>>>(agg1, xb, W1lt, W1rt, b1, h1t);

    // pooled layer-2 coefficients + GEMM
    k_buildw_s<<<1024, 256, 0, stream>>>(ei, batch, invdeg, Wbt_f);
    k_castw<<<(128 * NN / 4 + 255) / 256, 256, 0, stream>>>((const float4*)Wbt_f, (ushort4*)Wbt);
    dim3 g2((NN + KCHUNK - 1) / KCHUNK, HID / 128);
    k_poolg<<<g2, 256, 0, stream>>>(Wbt, h1t, P);

    k_head<<<NG, 256, 0, stream>>>(P, gcnt, gattr, W2l, b2, W2r, Wf1, bf1, Wf2, bf2v, out);
}

// Round 6
// 580.661 us; speedup vs baseline: 1.6661x; 1.3592x over previous
//
#include <hip/hip_runtime.h>
#include <stdint.h>

#define NN 100000
#define NE 1600000
#define NG 64
#define DIN 128
#define HID 256
#define NATTR 8
#define SL_NODES 12500  // NN / 8 slices (XCD-pinned scatter)

typedef unsigned short u16;
typedef __attribute__((ext_vector_type(8))) short s16x8;
typedef __attribute__((ext_vector_type(4))) float f32x4;

__device__ __forceinline__ int imaxi(int a, int b) { return a > b ? a : b; }
__device__ __forceinline__ u16 f2bf(float f) {
    unsigned u = __float_as_uint(f);
    unsigned r = (u + 0x7fffu + ((u >> 16) & 1u)) >> 16;  // RNE
    return (u16)r;
}

// ---------------- init: zero Wbt_f (51.2 MB), P8 (1 MB), deg, gcnt ----------------

__global__ void k_init(float4* __restrict__ Wbt4, float4* __restrict__ P84,
                       int4* __restrict__ deg4, int4* __restrict__ gcnt4) {
    int i = blockIdx.x * 256 + threadIdx.x;
    float4 z = make_float4(0.f, 0.f, 0.f, 0.f);
    if (i < 128 * NN / 4) Wbt4[i] = z;
    if (i < 8 * 128 * HID / 4) P84[i] = z;
    if (i < NN / 4) deg4[i] = make_int4(0, 0, 0, 0);
    if (i < NG / 4) gcnt4[i] = make_int4(0, 0, 0, 0);
}

// ---------------- prep: cast x->bf16, transpose W1 -> [n][k] bf16, sliced count ----------------

#define CB 12756     // cast/tw blocks: (NN*DIN/4 + 65536)/256
#define CNTB 782     // count blocks per slice group

__global__ void k_prep(const float4* __restrict__ x4, ushort4* __restrict__ xb4,
                       const float* __restrict__ W1l, const float* __restrict__ W1r,
                       u16* __restrict__ W1lt, u16* __restrict__ W1rt,
                       const int* __restrict__ ei, int* __restrict__ deg) {
    int b = blockIdx.x;
    if (b < CB) {
        int i = b * 256 + threadIdx.x;
        const int NX4 = NN * DIN / 4;  // 3,200,000
        if (i < NX4) {
            float4 v = x4[i];
            ushort4 o;
            o.x = f2bf(v.x); o.y = f2bf(v.y); o.z = f2bf(v.z); o.w = f2bf(v.w);
            xb4[i] = o;
        } else {
            int j = i - NX4;
            if (j < 32768) {
                int n = j >> 7, k = j & 127;
                W1lt[j] = f2bf(W1l[k * HID + n]);
            } else if (j < 65536) {
                int jj = j - 32768;
                int n = jj >> 7, k = jj & 127;
                W1rt[jj] = f2bf(W1r[k * HID + n]);
            }
        }
    } else {
        int k = b - CB;
        int g = k & 7, bi = k >> 3;
        int lo = g * SL_NODES, hi = lo + SL_NODES;
        const int stride = CNTB * 256;
        for (int e = bi * 256 + threadIdx.x; e < NE; e += stride) {
            int d = __builtin_nontemporal_load(&ei[NE + e]);
            if (d >= lo && d < hi) atomicAdd(&deg[d], 1);
        }
    }
}

// ---------------- scans ----------------

__global__ void k_scan_part(const int* __restrict__ deg, int* __restrict__ part) {
    __shared__ int red[256];
    int t = threadIdx.x;
    int base = blockIdx.x * 1024 + t * 4;
    int s = 0;
#pragma unroll
    for (int j = 0; j < 4; j++) { int i = base + j; s += (i < NN) ? deg[i] : 0; }
    red[t] = s; __syncthreads();
    for (int off = 128; off > 0; off >>= 1) {
        if (t < off) red[t] += red[t + off];
        __syncthreads();
    }
    if (t == 0) part[blockIdx.x] = red[0];
}

__global__ void k_scan_top(const int* __restrict__ part, int* __restrict__ poff, int nchunks) {
    if (threadIdx.x == 0) {
        int run = 0;
        for (int i = 0; i < nchunks; i++) { poff[i] = run; run += part[i]; }
    }
}

// also: invdeg, gcnt, and the PH indicator rows of Wbt_f (rows 64..127)
__global__ void k_scan_final(const int* __restrict__ deg, const int* __restrict__ poff,
                             int* __restrict__ rowptr, int* __restrict__ cursor,
                             float* __restrict__ invdeg, const int* __restrict__ batch,
                             int* __restrict__ gcnt, float* __restrict__ Wbt_f) {
    __shared__ int arr[256];
    __shared__ int lc[NG];
    int t = threadIdx.x;
    int base = blockIdx.x * 1024 + t * 4;
    if (t < NG) lc[t] = 0;
    int v[4];
#pragma unroll
    for (int j = 0; j < 4; j++) { int i = base + j; v[j] = (i < NN) ? deg[i] : 0; }
    int T = v[0] + v[1] + v[2] + v[3];
    arr[t] = T; __syncthreads();
    for (int off = 1; off < 256; off <<= 1) {
        int add = (t >= off) ? arr[t - off] : 0;
        __syncthreads();
        arr[t] += add;
        __syncthreads();
    }
    int ex = poff[blockIdx.x] + arr[t] - T;
    int pre = 0;
#pragma unroll
    for (int j = 0; j < 4; j++) {
        int i = base + j;
        int val = ex + pre;
        if (i <= NN) rowptr[i] = val;
        if (i < NN) {
            cursor[i] = val;
            invdeg[i] = 1.0f / (float)imaxi(v[j], 1);
            int g = batch[i];
            atomicAdd(&lc[g], 1);
            Wbt_f[(size_t)(NG + g) * NN + i] = 1.0f;  // indicator (PH) row
        }
        pre += v[j];
    }
    __syncthreads();
    if (t < NG && lc[t] > 0) atomicAdd(&gcnt[t], lc[t]);
}

// ---------------- fused XCD-sliced edge pass: CSR fill (by dst) + Wbt atomics (by src) ----------------
// One ei stream; each slice-group's scattered writes confined to ~L2-sized windows.

__global__ void k_edge_s(const int* __restrict__ ei, int* __restrict__ cursor,
                         int* __restrict__ col, const int* __restrict__ batch,
                         const float* __restrict__ invdeg, float* __restrict__ Wbt_f) {
    int k = blockIdx.x;
    int g = k & 7, bi = k >> 3;
    int lo = g * SL_NODES, hi = lo + SL_NODES;
    const int stride = (256 >> 0) * 256 * 8 / 8;  // (gridDim/8)*256 = 256*256
    for (int e = bi * 256 + threadIdx.x; e < NE; e += 256 * 256) {
        int s = __builtin_nontemporal_load(&ei[e]);
        int d = __builtin_nontemporal_load(&ei[NE + e]);
        if (d >= lo && d < hi) col[atomicAdd(&cursor[d], 1)] = s;
        if (s >= lo && s < hi) atomicAdd(&Wbt_f[(size_t)batch[d] * NN + s], invdeg[d]);
    }
    (void)stride;
}

// ---------------- layer-1 mean aggregation (full-row CSR gather, R3 form + unroll2) ----------------
// one wave per node; lane handles 2 bf16 (one dword); 256 B coalesced row reads.

__global__ void k_agg(const unsigned* __restrict__ xb, unsigned* __restrict__ agg1,
                      const int* __restrict__ rowptr, const int* __restrict__ col) {
    int node = blockIdx.x * 4 + (threadIdx.x >> 6);
    int lane = threadIdx.x & 63;
    if (node >= NN) return;
    int s = rowptr[node], e = rowptr[node + 1];
    float ax = 0.f, ay = 0.f;
    int i = s;
    for (; i + 2 <= e; i += 2) {
        int u0 = col[i], u1 = col[i + 1];
        unsigned w0 = xb[(size_t)u0 * 64 + lane];
        unsigned w1 = xb[(size_t)u1 * 64 + lane];
        ax += __uint_as_float(w0 << 16);
        ay += __uint_as_float(w0 & 0xffff0000u);
        ax += __uint_as_float(w1 << 16);
        ay += __uint_as_float(w1 & 0xffff0000u);
    }
    if (i < e) {
        int u = col[i];
        unsigned w = xb[(size_t)u * 64 + lane];
        ax += __uint_as_float(w << 16);
        ay += __uint_as_float(w & 0xffff0000u);
    }
    float inv = 1.f / (float)imaxi(e - s, 1);
    unsigned o = (((unsigned)f2bf(ay * inv)) << 16) | (unsigned)f2bf(ax * inv);
    agg1[(size_t)node * 64 + lane] = o;
}

// ---------------- MFMA GEMM1: h1t = relu(agg1@W1l + x@W1r + b1)^T ----------------

__global__ __launch_bounds__(256) void k_gemm1(
    const u16* __restrict__ agg1, const u16* __restrict__ xb,
    const u16* __restrict__ W1lt, const u16* __restrict__ W1rt,
    const float* __restrict__ b1, u16* __restrict__ h1t) {
    __shared__ u16 As[128][40];
    __shared__ u16 Bs[128][40];
    int t = threadIdx.x;
    int m0 = blockIdx.x * 128;
    int n0 = blockIdx.y * 128;
    int wave = t >> 6, lane = t & 63;
    int wm = wave & 1, wn = wave >> 1;
    int lm = lane & 15, quad = lane >> 4;
    f32x4 acc[4][4] = {};
    const u16* Ap = agg1;
    const u16* Bp = W1lt;
#pragma unroll
    for (int ph = 0; ph < 2; ph++) {
        for (int k0 = 0; k0 < DIN; k0 += 32) {
#pragma unroll
            for (int i = 0; i < 2; i++) {
                int flat = t + i * 256;
                int r = flat >> 2, q = flat & 3;
                int m = m0 + r;
                uint4 v = {0u, 0u, 0u, 0u};
                if (m < NN) v = *(const uint4*)(Ap + (size_t)m * DIN + k0 + q * 8);
                *(uint4*)&As[r][q * 8] = v;
                uint4 w = *(const uint4*)(Bp + (size_t)(n0 + r) * DIN + k0 + q * 8);
                *(uint4*)&Bs[r][q * 8] = w;
            }
            __syncthreads();
            s16x8 af[4], bfr[4];
#pragma unroll
            for (int i = 0; i < 4; i++) {
                af[i]  = *(const s16x8*)&As[wm * 64 + i * 16 + lm][quad * 8];
                bfr[i] = *(const s16x8*)&Bs[wn * 64 + i * 16 + lm][quad * 8];
            }
#pragma unroll
            for (int mi = 0; mi < 4; mi++)
#pragma unroll
                for (int ni = 0; ni < 4; ni++)
                    acc[mi][ni] = __builtin_amdgcn_mfma_f32_16x16x32_bf16(
                        af[mi], bfr[ni], acc[mi][ni], 0, 0, 0);
            __syncthreads();
        }
        Ap = xb; Bp = W1rt;
    }
#pragma unroll
    for (int ni = 0; ni < 4; ni++) {
        int colf = n0 + wn * 64 + ni * 16 + lm;  // feature
        float bias = b1[colf];
#pragma unroll
        for (int mi = 0; mi < 4; mi++) {
            int row = m0 + wm * 64 + mi * 16 + quad * 4;  // node
            if (row < NN) {
                ushort4 o;
                o.x = f2bf(fmaxf(acc[mi][ni][0] + bias, 0.f));
                o.y = f2bf(fmaxf(acc[mi][ni][1] + bias, 0.f));
                o.z = f2bf(fmaxf(acc[mi][ni][2] + bias, 0.f));
                o.w = f2bf(fmaxf(acc[mi][ni][3] + bias, 0.f));
                *(ushort4*)(h1t + (size_t)colf * NN + row) = o;
            }
        }
    }
}

// ---------------- pool GEMM (split-K MFMA): P = Wbt_f(bf16-cvt) @ h1t^T ----------------
// A staged from f32 with in-register bf16 convert (no separate cast kernel).
// Epilogue atomics go to per-slice P copy (blockIdx.x & 7) to avoid cross-XCD contention.

#define KCHUNK 1024

__global__ __launch_bounds__(256) void k_poolg(
    const float* __restrict__ Wbt_f, const u16* __restrict__ h1t, float* __restrict__ P8) {
    __shared__ u16 As[128][40];
    __shared__ u16 Bs[128][40];
    int t = threadIdx.x;
    int kbase = blockIdx.x * KCHUNK;
    int n0 = blockIdx.y * 128;
    int krem = NN - kbase;
    int ksteps = (krem < KCHUNK ? krem : KCHUNK) >> 5;
    int wave = t >> 6, lane = t & 63;
    int wm = wave & 1, wn = wave >> 1;
    int lm = lane & 15, quad = lane >> 4;
    float* P = P8 + (size_t)(blockIdx.x & 7) * 128 * HID;
    f32x4 acc[4][4] = {};
    for (int ks = 0; ks < ksteps; ks++) {
        int k0 = kbase + ks * 32;
#pragma unroll
        for (int i = 0; i < 2; i++) {
            int flat = t + i * 256;
            int r = flat >> 2, q = flat & 3;
            const float4* ap = (const float4*)(Wbt_f + (size_t)r * NN + k0 + q * 8);
            float4 a0 = ap[0], a1 = ap[1];
            ushort4 lo, hi;
            lo.x = f2bf(a0.x); lo.y = f2bf(a0.y); lo.z = f2bf(a0.z); lo.w = f2bf(a0.w);
            hi.x = f2bf(a1.x); hi.y = f2bf(a1.y); hi.z = f2bf(a1.z); hi.w = f2bf(a1.w);
            *(ushort4*)&As[r][q * 8] = lo;
            *(ushort4*)&As[r][q * 8 + 4] = hi;
            uint4 w = *(const uint4*)(h1t + (size_t)(n0 + r) * NN + k0 + q * 8);
            *(uint4*)&Bs[r][q * 8] = w;
        }
        __syncthreads();
        s16x8 af[4], bfr[4];
#pragma unroll
        for (int i = 0; i < 4; i++) {
            af[i]  = *(const s16x8*)&As[wm * 64 + i * 16 + lm][quad * 8];
            bfr[i] = *(const s16x8*)&Bs[wn * 64 + i * 16 + lm][quad * 8];
        }
#pragma unroll
        for (int mi = 0; mi < 4; mi++)
#pragma unroll
            for (int ni = 0; ni < 4; ni++)
                acc[mi][ni] = __builtin_amdgcn_mfma_f32_16x16x32_bf16(
                    af[mi], bfr[ni], acc[mi][ni], 0, 0, 0);
        __syncthreads();
    }
#pragma unroll
    for (int mi = 0; mi < 4; mi++)
#pragma unroll
        for (int ni = 0; ni < 4; ni++) {
            int gcol = wm * 64 + mi * 16 + quad * 4;
            int feat = n0 + wn * 64 + ni * 16 + lm;
#pragma unroll
            for (int r = 0; r < 4; r++)
                atomicAdd(&P[(gcol + r) * HID + feat], acc[mi][ni][r]);
        }
}

// ---------------- head ----------------

__global__ void k_head(const float* __restrict__ P8, const int* __restrict__ gcnt,
                       const float* __restrict__ gattr,
                       const float* __restrict__ W2l, const float* __restrict__ b2,
                       const float* __restrict__ W2r,
                       const float* __restrict__ Wf1, const float* __restrict__ bf1,
                       const float* __restrict__ Wf2, const float* __restrict__ bf2v,
                       float* __restrict__ out) {
    __shared__ float pa[HID], ph[HID], gv[HID + NATTR];
    __shared__ float red[256];
    int g = blockIdx.x, t = threadIdx.x;
    float sa = 0.f, sh = 0.f;
#pragma unroll
    for (int c = 0; c < 8; c++) {
        sa += P8[(size_t)c * 128 * HID + g * HID + t];
        sh += P8[(size_t)c * 128 * HID + (NG + g) * HID + t];
    }
    pa[t] = sa; ph[t] = sh;
    __syncthreads();
    float s = 0.f;
    for (int k = 0; k < HID; k++)
        s += pa[k] * W2l[k * HID + t] + ph[k] * W2r[k * HID + t];
    float invc = 1.f / (float)imaxi(gcnt[g], 1);
    gv[t] = s * invc + b2[t];
    if (t < NATTR) gv[HID + t] = gattr[g * NATTR + t];
    __syncthreads();
    float h = bf1[t];
    for (int k = 0; k < HID + NATTR; k++) h += gv[k] * Wf1[k * HID + t];
    h = fmaxf(h, 0.f);
    red[t] = h * Wf2[t];
    __syncthreads();
    for (int off = 128; off > 0; off >>= 1) {
        if (t < off) red[t] += red[t + off];
        __syncthreads();
    }
    if (t == 0) out[g] = red[0] + bf2v[0];
}

// ---------------- launch ----------------

extern "C" void kernel_launch(void* const* d_in, const int* in_sizes, int n_in,
                              void* d_out, int out_size, void* d_ws, size_t ws_size,
                              hipStream_t stream) {
    (void)in_sizes; (void)n_in; (void)out_size; (void)ws_size;
    const float* x     = (const float*)d_in[0];
    const int*   ei    = (const int*)d_in[1];
    const int*   batch = (const int*)d_in[2];
    const float* gattr = (const float*)d_in[3];
    const float* W1l   = (const float*)d_in[4];
    const float* b1    = (const float*)d_in[5];
    const float* W1r   = (const float*)d_in[6];
    const float* W2l   = (const float*)d_in[7];
    const float* b2    = (const float*)d_in[8];
    const float* W2r   = (const float*)d_in[9];
    const float* Wf1   = (const float*)d_in[10];
    const float* bf1   = (const float*)d_in[11];
    const float* Wf2   = (const float*)d_in[12];
    const float* bf2v  = (const float*)d_in[13];
    float* out = (float*)d_out;

    uint8_t* w = (uint8_t*)d_ws;
    size_t off = 0;
    auto alloc = [&](size_t bytes) -> void* {
        void* p = w + off;
        off += (bytes + 255) & ~(size_t)255;
        return p;
    };
    u16*   xb     = (u16*)alloc((size_t)NN * DIN * 2);     // 25.6 MB
    u16*   agg1   = (u16*)alloc((size_t)NN * DIN * 2);     // 25.6 MB
    u16*   h1t    = (u16*)alloc((size_t)NN * HID * 2);     // 51.2 MB
    float* Wbt_f  = (float*)alloc((size_t)128 * NN * 4);   // 51.2 MB
    u16*   W1lt   = (u16*)alloc((size_t)HID * DIN * 2);
    u16*   W1rt   = (u16*)alloc((size_t)HID * DIN * 2);
    int*   deg    = (int*)alloc((size_t)NN * 4);
    float* invdeg = (float*)alloc((size_t)NN * 4);
    int*   rowptr = (int*)alloc((size_t)(NN + 1) * 4);
    int*   cursor = (int*)alloc((size_t)NN * 4);
    int*   col    = (int*)alloc((size_t)NE * 4);           // 6.4 MB
    int*   part   = (int*)alloc(128 * 4);
    int*   poff   = (int*)alloc(128 * 4);
    float* P8     = (float*)alloc((size_t)8 * 128 * HID * 4);  // 1 MB
    int*   gcnt   = (int*)alloc(NG * 4);

    const int nchunks = (NN + 1023) / 1024;  // 98

    k_init<<<(128 * NN / 4 + 255) / 256, 256, 0, stream>>>(
        (float4*)Wbt_f, (float4*)P8, (int4*)deg, (int4*)gcnt);
    k_prep<<<CB + 8 * CNTB, 256, 0, stream>>>(
        (const float4*)x, (ushort4*)xb, W1l, W1r, W1lt, W1rt, ei, deg);

    k_scan_part<<<nchunks, 256, 0, stream>>>(deg, part);
    k_scan_top<<<1, 64, 0, stream>>>(part, poff, nchunks);
    k_scan_final<<<nchunks, 256, 0, stream>>>(deg, poff, rowptr, cursor, invdeg,
                                              batch, gcnt, Wbt_f);
    k_edge_s<<<2048, 256, 0, stream>>>(ei, cursor, col, batch, invdeg, Wbt_f);

    // layer 1
    k_agg<<<NN / 4, 256, 0, stream>>>((const unsigned*)xb, (unsigned*)agg1, rowptr, col);
    dim3 g1((NN + 127) / 128, HID / 128);
    k_gemm1<<<g1, 256, 0, stream>>>(agg1, xb, W1lt, W1rt, b1, h1t);

    // pooled layer-2 GEMM (A converted from f32 in-kernel)
    dim3 g2((NN + KCHUNK - 1) / KCHUNK, HID / 128);
    k_poolg<<<g2, 256, 0, stream>>>(Wbt_f, h1t, P8);

    k_head<<<NG, 256, 0, stream>>>(P8, gcnt, gattr, W2l, b2, W2r, Wf1, bf1, Wf2, bf2v, out);
}